// Round 4
// baseline (52.669 us; speedup 1.0000x reference)
//
#include <hip/hip_runtime.h>
#include <math.h>

#define NPARTS 64
#define CELL 28
#define CDIM 2048
#define BDIM 256

// k_main dis-part geometry: block = 4 images x one 64-channel slice
#define NSPLIT 32                       // 2048 / 64 channel slices
#define DIS_BLOCKS (BDIM / 4 * NSPLIT)  // 2048

// ---- d_ws layout (float offsets) ----
#define WS_SAME   0
#define WS_SUM3   (WS_SAME + BDIM * NPARTS)             // 16384
#define WS_PART   (WS_SUM3 + BDIM * NPARTS)             // 32768, size 2048*192
#define WS_MBT    (WS_PART + DIS_BLOCKS * 3 * NPARTS)   // 425984
#define WS_MMT    (WS_MBT + CDIM * NPARTS)
#define WS_MNT    (WS_MMT + CDIM * NPARTS)
#define WS_CELL   (WS_MNT + CDIM * NPARTS)              // int cells, 16384

#define PREP_BLOCKS 1600   // 1536 transpose + 64 cell blocks = 409600 threads

// ---------------------------------------------------------------------------
// Prep only (fast, unblocks k_main ASAP): transpose means [p][c] ->
// [c/4][p][4] so lane=p reads float4 coalesced; precompute cell[b][p].
// ---------------------------------------------------------------------------
__global__ __launch_bounds__(256) void k_front(
    const float* __restrict__ mb, const float* __restrict__ mm,
    const float* __restrict__ mn, const int* __restrict__ cx,
    const int* __restrict__ cy, float* __restrict__ ws)
{
    const int tid = blockIdx.x * 256 + threadIdx.x;
    const int NM = CDIM * NPARTS;               // 131072 = 2^17
    if (tid < 3 * NM) {
        const int kind = tid >> 17;
        const int idx  = tid & (NM - 1);
        const int p = idx >> 11;
        const int c = idx & (CDIM - 1);
        const float* src = (kind == 0) ? mb : (kind == 1) ? mm : mn;
        float* dst = ws + ((kind == 0) ? WS_MBT : (kind == 1) ? WS_MMT : WS_MNT);
        dst[((c >> 2) << 8) + (p << 2) + (c & 3)] = src[idx];
    } else {
        const int t2 = tid - 3 * NM;            // < BDIM*NPARTS
        const int b = t2 & (BDIM - 1);
        const int p = t2 >> 8;
        const int x = cx[t2] / CELL;
        const int y = cy[t2] / CELL;
        ((int*)ws)[WS_CELL + b * NPARTS + p] = x * 8 + y;
    }
}

// ---------------------------------------------------------------------------
// Main kernel.
// Blocks [0,2048): per-(b,p) squared distances. Block g: channel slice
// s = g&31 (64 channels), images b0..b0+3 with b0 = (g>>5)*4; wave w owns
// image b0+w, lane = part p. The 4 waves read IDENTICAL mean addresses
// (L1 reuse) and each wave writes its own partial directly - no LDS
// reduction needed. fm reads are fully coalesced (256 B per load);
// ds_bpermute redistributes cell values to parts.
// Blocks [2048,2304): distances_im + val for image g-2048 (independent
// of prep, runs concurrently with dis work).
// ---------------------------------------------------------------------------
__global__ __launch_bounds__(256) void k_main(
    const float* __restrict__ fm,
    const float* __restrict__ emb,
    const float* __restrict__ meb, const float* __restrict__ mem_,
    const float* __restrict__ men,
    float* __restrict__ ws, float* __restrict__ out)
{
    const int g = blockIdx.x;
    const int t = threadIdx.x;
    __shared__ float red[3][4];

    if (g < DIS_BLOCKS) {
        const int lane = t & 63, w = t >> 6;
        const int s  = g & (NSPLIT - 1);
        const int b  = ((g >> 5) << 2) + w;

        const int cell  = ((const int*)ws)[WS_CELL + b * NPARTS + lane];
        const int baddr = cell << 2;

        const int c0 = s * 64;
        const float* fmb = fm + (size_t)b * (CDIM * 64) + (size_t)c0 * 64;
        const float4* mbt = (const float4*)(ws + WS_MBT) + ((c0 >> 2) << 6) + lane;
        const float4* mmt = (const float4*)(ws + WS_MMT) + ((c0 >> 2) << 6) + lane;
        const float4* mnt = (const float4*)(ws + WS_MNT) + ((c0 >> 2) << 6) + lane;

        float a0 = 0.f, a1 = 0.f, a2 = 0.f;
        #pragma unroll 4
        for (int k = 0; k < 16; ++k) {          // 4 channels per iter
            const float* r = fmb + k * 256;
            float v0 = r[lane];
            float v1 = r[64 + lane];
            float v2 = r[128 + lane];
            float v3 = r[192 + lane];
            float4 m0 = mbt[k * 64];
            float4 m1 = mmt[k * 64];
            float4 m2 = mnt[k * 64];
            float u0 = __int_as_float(__builtin_amdgcn_ds_bpermute(baddr, __float_as_int(v0)));
            float u1 = __int_as_float(__builtin_amdgcn_ds_bpermute(baddr, __float_as_int(v1)));
            float u2 = __int_as_float(__builtin_amdgcn_ds_bpermute(baddr, __float_as_int(v2)));
            float u3 = __int_as_float(__builtin_amdgcn_ds_bpermute(baddr, __float_as_int(v3)));
            float d;
            d = u0 - m0.x; a0 += d * d;  d = u1 - m0.y; a0 += d * d;
            d = u2 - m0.z; a0 += d * d;  d = u3 - m0.w; a0 += d * d;
            d = u0 - m1.x; a1 += d * d;  d = u1 - m1.y; a1 += d * d;
            d = u2 - m1.z; a1 += d * d;  d = u3 - m1.w; a1 += d * d;
            d = u0 - m2.x; a2 += d * d;  d = u1 - m2.y; a2 += d * d;
            d = u2 - m2.z; a2 += d * d;  d = u3 - m2.w; a2 += d * d;
        }

        float* po = ws + WS_PART + (size_t)(b * NSPLIT + s) * 192;
        po[lane] = a0; po[64 + lane] = a1; po[128 + lane] = a2;
        return;
    }

    // ---- distances_im + val ----
    const int b = g - DIS_BLOCKS;
    const float* e = emb + (size_t)b * CDIM;

    float sb = 0.f, sm = 0.f, sn = 0.f;
    for (int c = t; c < CDIM; c += 256) {
        float v = e[c];
        float d0 = v - meb[c];  sb += d0 * d0;
        float d1 = v - mem_[c]; sm += d1 * d1;
        float d2 = v - men[c];  sn += d2 * d2;
    }
    for (int off = 32; off; off >>= 1) {
        sb += __shfl_down(sb, off);
        sm += __shfl_down(sm, off);
        sn += __shfl_down(sn, off);
    }
    const int wave = t >> 6;
    if ((t & 63) == 0) { red[0][wave] = sb; red[1][wave] = sm; red[2][wave] = sn; }
    __syncthreads();
    if (t == 0) {
        float tb = red[0][0] + red[0][1] + red[0][2] + red[0][3];
        float tm = red[1][0] + red[1][1] + red[1][2] + red[1][3];
        float tn = red[2][0] + red[2][1] + red[2][2] + red[2][3];
        float db = sqrtf(tb), dm = sqrtf(tm), dn = sqrtf(tn);
        out[b * 3 + 0] = db;
        out[b * 3 + 1] = dm;
        out[b * 3 + 2] = dn;
        int idx = 0; float best = db;
        if (dm < best) { best = dm; idx = 1; }
        if (dn < best) { idx = 2; }
        out[3 * BDIM + b] = (float)idx;
    }
}

// ---------------------------------------------------------------------------
// Combine 32 channel-slices -> sqrt -> same/sum3
// ---------------------------------------------------------------------------
__global__ __launch_bounds__(256) void k_combine(
    const int* __restrict__ labels, float* __restrict__ ws)
{
    const int gid = blockIdx.x * 256 + threadIdx.x;   // 16384
    const int b = gid >> 6, p = gid & 63;
    const float* pp = ws + WS_PART + (size_t)(b * NSPLIT) * 192;
    float s0 = 0.f, s1 = 0.f, s2 = 0.f;
    #pragma unroll
    for (int s = 0; s < NSPLIT; ++s) {
        s0 += pp[s * 192 + p];
        s1 += pp[s * 192 + 64 + p];
        s2 += pp[s * 192 + 128 + p];
    }
    float db = sqrtf(s0), dm = sqrtf(s1), dn = sqrtf(s2);
    const int lab = labels[b];
    ws[WS_SAME + gid] = (lab == 0) ? db : ((lab == 1) ? dm : dn);
    ws[WS_SUM3 + gid] = db + dm + dn;
}

// ---------------------------------------------------------------------------
// Deterministic final loss (single block, 512 threads)
// ---------------------------------------------------------------------------
__global__ __launch_bounds__(512) void k_loss(
    const float* __restrict__ ws, float* __restrict__ out)
{
    const int t = threadIdx.x;
    const int N = BDIM * NPARTS;
    const float* same = ws + WS_SAME;
    const float* sum3 = ws + WS_SUM3;

    double s3 = 0.0, ss = 0.0;
    for (int i = t; i < N; i += 512) { s3 += (double)sum3[i]; ss += (double)same[i]; }

    __shared__ double r1[512], r2[512];
    r1[t] = s3; r2[t] = ss;
    __syncthreads();
    for (int off = 256; off; off >>= 1) {
        if (t < off) { r1[t] += r1[t + off]; r2[t] += r2[t + off]; }
        __syncthreads();
    }
    __shared__ float dmS;
    if (t == 0) dmS = (float)((r1[0] - r2[0]) / (double)(BDIM * 2 * NPARTS));
    __syncthreads();
    const float dmean = dmS;

    double sl = 0.0;
    for (int i = t; i < N; i += 512) {
        float v = 1.0f + same[i] - dmean;
        sl += (v > 0.f) ? (double)v : 0.0;
    }
    r1[t] = sl;
    __syncthreads();
    for (int off = 256; off; off >>= 1) {
        if (t < off) r1[t] += r1[t + off];
        __syncthreads();
    }
    if (t == 0) out[3 * BDIM + BDIM] = (float)(r1[0] / (double)N);
}

extern "C" void kernel_launch(void* const* d_in, const int* in_sizes, int n_in,
                              void* d_out, int out_size, void* d_ws, size_t ws_size,
                              hipStream_t stream)
{
    const int*   labels = (const int*)  d_in[0];
    const float* emb    = (const float*)d_in[1];
    const float* fm     = (const float*)d_in[2];
    const float* mb     = (const float*)d_in[3];
    const float* mm     = (const float*)d_in[4];
    const float* mn     = (const float*)d_in[5];
    const int*   cx     = (const int*)  d_in[6];
    const int*   cy     = (const int*)  d_in[7];
    const float* meb    = (const float*)d_in[8];
    const float* mem_   = (const float*)d_in[9];
    const float* men    = (const float*)d_in[10];

    float* out = (float*)d_out;
    float* ws  = (float*)d_ws;

    k_front<<<PREP_BLOCKS, 256, 0, stream>>>(mb, mm, mn, cx, cy, ws);
    k_main<<<DIS_BLOCKS + BDIM, 256, 0, stream>>>(fm, emb, meb, mem_, men, ws, out);
    k_combine<<<BDIM * NPARTS / 256, 256, 0, stream>>>(labels, ws);
    k_loss<<<1, 512, 0, stream>>>(ws, out);
}